// Round 1
// baseline (16080.168 us; speedup 1.0000x reference)
//
#include <hip/hip_runtime.h>
#include <math.h>

#define NB 512
#define SL 1024
#define NW 256

__device__ __forceinline__ float rcp_f(float v) { return __builtin_amdgcn_rcpf(v); }

__global__ __launch_bounds__(1024, 4) void gru_logprob_kernel(
    const float* __restrict__ x,
    const float* __restrict__ w_ih,
    const float* __restrict__ w_hh,
    const float* __restrict__ b_ih,
    const float* __restrict__ b_hh,
    const float* __restrict__ fc_w,
    const float* __restrict__ fc_b,
    float* __restrict__ out)
{
    const int tid = threadIdx.x;
    const int o   = tid >> 2;      // hidden unit 0..255
    const int kc  = tid & 3;       // k-chunk 0..3
    const int kb  = kc * 64;
    const int row0 = blockIdx.x * 2;

    __shared__ float hbuf[2][2][NW];     // double-buffered hidden state (2 rows)
    __shared__ float xrow[2][SL];        // staged spin rows
    __shared__ float dpart[2][2][16];    // per-wave d partials, double-buffered

    // stage x rows (coalesced)
    xrow[0][tid] = x[(size_t)row0 * SL + tid];
    xrow[1][tid] = x[(size_t)(row0 + 1) * SL + tid];
    if (tid < 2 * NW) hbuf[0][tid >> 8][tid & (NW - 1)] = 0.0f;

    // ---- persistent weights in registers: 3 gates x 64 k = 192 VGPRs ----
    float wr[64], wz[64], wn[64];
    {
        const float* pr = w_hh + (size_t)(o)          * NW + kb;
        const float* pz = w_hh + (size_t)(NW + o)     * NW + kb;
        const float* pn = w_hh + (size_t)(2 * NW + o) * NW + kb;
        #pragma unroll
        for (int j = 0; j < 64; j += 4) {
            float4 a = *(const float4*)(pr + j);
            wr[j] = a.x; wr[j+1] = a.y; wr[j+2] = a.z; wr[j+3] = a.w;
            float4 b = *(const float4*)(pz + j);
            wz[j] = b.x; wz[j+1] = b.y; wz[j+2] = b.z; wz[j+3] = b.w;
            float4 c = *(const float4*)(pn + j);
            wn[j] = c.x; wn[j+1] = c.y; wn[j+2] = c.z; wn[j+3] = c.w;
        }
    }

    // input-side gate vectors: gi = gm + m_prev * gd  (m_prev in {0,1}, 0.5 at t=0)
    // b_hh folded into gm for r,z gates; n-gate's b_hh stays with matvec (multiplied by r)
    const float gdr = w_ih[2*o]              - w_ih[2*o + 1];
    const float gmr = w_ih[2*o + 1]          + b_ih[o]        + b_hh[o];
    const float gdz = w_ih[2*(NW+o)]         - w_ih[2*(NW+o)+1];
    const float gmz = w_ih[2*(NW+o)+1]       + b_ih[NW+o]     + b_hh[NW+o];
    const float gdn = w_ih[2*(2*NW+o)]       - w_ih[2*(2*NW+o)+1];
    const float gmn = w_ih[2*(2*NW+o)+1]     + b_ih[2*NW+o];
    const float bhn = b_hh[2*NW+o];
    const float wd  = fc_w[o] - fc_w[NW + o];        // fc_w[0][o]-fc_w[1][o]
    const float bd  = fc_b[0] - fc_b[1];

    float h0 = 0.0f, h1 = 0.0f;        // this thread's h[o] for rows 0,1
    float lp0 = 0.0f, lp1 = 0.0f;      // accumulated log-prob (thread 0 uses)

    __syncthreads();

    #pragma unroll 1
    for (int t = 0; t < SL; ++t) {
        const int cur = t & 1, nxt = cur ^ 1;

        float ar0 = 0.f, az0 = 0.f, an0 = 0.f;
        float ar1 = 0.f, az1 = 0.f, an1 = 0.f;
        #pragma unroll
        for (int j = 0; j < 64; j += 4) {
            float4 a0 = *(const float4*)&hbuf[cur][0][kb + j];
            float4 a1 = *(const float4*)&hbuf[cur][1][kb + j];
            ar0 = fmaf(wr[j+0], a0.x, ar0); ar0 = fmaf(wr[j+1], a0.y, ar0);
            ar0 = fmaf(wr[j+2], a0.z, ar0); ar0 = fmaf(wr[j+3], a0.w, ar0);
            az0 = fmaf(wz[j+0], a0.x, az0); az0 = fmaf(wz[j+1], a0.y, az0);
            az0 = fmaf(wz[j+2], a0.z, az0); az0 = fmaf(wz[j+3], a0.w, az0);
            an0 = fmaf(wn[j+0], a0.x, an0); an0 = fmaf(wn[j+1], a0.y, an0);
            an0 = fmaf(wn[j+2], a0.z, an0); an0 = fmaf(wn[j+3], a0.w, an0);
            ar1 = fmaf(wr[j+0], a1.x, ar1); ar1 = fmaf(wr[j+1], a1.y, ar1);
            ar1 = fmaf(wr[j+2], a1.z, ar1); ar1 = fmaf(wr[j+3], a1.w, ar1);
            az1 = fmaf(wz[j+0], a1.x, az1); az1 = fmaf(wz[j+1], a1.y, az1);
            az1 = fmaf(wz[j+2], a1.z, az1); az1 = fmaf(wz[j+3], a1.w, az1);
            an1 = fmaf(wn[j+0], a1.x, an1); an1 = fmaf(wn[j+1], a1.y, an1);
            an1 = fmaf(wn[j+2], a1.z, an1); an1 = fmaf(wn[j+3], a1.w, an1);
        }
        // reduce over the 4 kc lanes (butterfly -> all lanes hold full sum)
        ar0 += __shfl_xor(ar0, 1); ar0 += __shfl_xor(ar0, 2);
        az0 += __shfl_xor(az0, 1); az0 += __shfl_xor(az0, 2);
        an0 += __shfl_xor(an0, 1); an0 += __shfl_xor(an0, 2);
        ar1 += __shfl_xor(ar1, 1); ar1 += __shfl_xor(ar1, 2);
        az1 += __shfl_xor(az1, 1); az1 += __shfl_xor(az1, 2);
        an1 += __shfl_xor(an1, 1); an1 += __shfl_xor(an1, 2);

        const float xp0 = (t == 0) ? 0.0f : xrow[0][t-1];
        const float xp1 = (t == 0) ? 0.0f : xrow[1][t-1];
        const float m0 = (xp0 + 1.0f) * 0.5f;
        const float m1 = (xp1 + 1.0f) * 0.5f;

        // row 0 gates
        float vr0 = fmaf(m0, gdr, gmr) + ar0;
        float rr0 = rcp_f(1.0f + __expf(-vr0));
        float vz0 = fmaf(m0, gdz, gmz) + az0;
        float zz0 = rcp_f(1.0f + __expf(-vz0));
        float un0 = fmaf(rr0, an0 + bhn, fmaf(m0, gdn, gmn));
        float ng0 = fmaf(-2.0f, rcp_f(1.0f + __expf(2.0f * un0)), 1.0f);  // tanh
        float h0n = fmaf(zz0, h0 - ng0, ng0);
        // row 1 gates
        float vr1 = fmaf(m1, gdr, gmr) + ar1;
        float rr1 = rcp_f(1.0f + __expf(-vr1));
        float vz1 = fmaf(m1, gdz, gmz) + az1;
        float zz1 = rcp_f(1.0f + __expf(-vz1));
        float un1 = fmaf(rr1, an1 + bhn, fmaf(m1, gdn, gmn));
        float ng1 = fmaf(-2.0f, rcp_f(1.0f + __expf(2.0f * un1)), 1.0f);
        float h1n = fmaf(zz1, h1 - ng1, ng1);

        h0 = h0n; h1 = h1n;

        // d = sum_o h[o]*wd[o]  (kc==0 lanes contribute, full-wave butterfly)
        float v0 = (kc == 0) ? h0n * wd : 0.0f;
        float v1 = (kc == 0) ? h1n * wd : 0.0f;
        #pragma unroll
        for (int s = 1; s < 64; s <<= 1) {
            v0 += __shfl_xor(v0, s);
            v1 += __shfl_xor(v1, s);
        }
        if ((tid & 63) == 0) {
            dpart[cur][0][tid >> 6] = v0;
            dpart[cur][1][tid >> 6] = v1;
        }
        if (kc == 0) {
            hbuf[nxt][0][o] = h0n;
            hbuf[nxt][1][o] = h1n;
        }
        __syncthreads();

        if (tid == 0) {
            float d0 = bd, d1 = bd;
            #pragma unroll
            for (int wv = 0; wv < 16; ++wv) {
                d0 += dpart[cur][0][wv];
                d1 += dpart[cur][1][wv];
            }
            const float xt0 = xrow[0][t], xt1 = xrow[1][t];
            const float u0 = (xt0 > 0.0f) ? -d0 : d0;   // u = -x*d
            const float u1 = (xt1 > 0.0f) ? -d1 : d1;
            // lp -= softplus(u) = max(u,0) + log(1+exp(-|u|))
            lp0 -= fmaxf(u0, 0.0f) + logf(1.0f + __expf(-fabsf(u0)));
            lp1 -= fmaxf(u1, 0.0f) + logf(1.0f + __expf(-fabsf(u1)));
        }
    }

    if (tid == 0) {
        out[row0]     = lp0;
        out[row0 + 1] = lp1;
    }
}

extern "C" void kernel_launch(void* const* d_in, const int* in_sizes, int n_in,
                              void* d_out, int out_size, void* d_ws, size_t ws_size,
                              hipStream_t stream) {
    const float* x    = (const float*)d_in[0];
    const float* w_ih = (const float*)d_in[1];
    const float* w_hh = (const float*)d_in[2];
    const float* b_ih = (const float*)d_in[3];
    const float* b_hh = (const float*)d_in[4];
    const float* fc_w = (const float*)d_in[5];
    const float* fc_b = (const float*)d_in[6];
    gru_logprob_kernel<<<NB / 2, 1024, 0, stream>>>(
        x, w_ih, w_hh, b_ih, b_hh, fc_w, fc_b, (float*)d_out);
}

// Round 2
// 1441.895 us; speedup vs baseline: 11.1521x; 11.1521x over previous
//
#include <hip/hip_runtime.h>
#include <math.h>

#define SL 1024
#define NW 256

typedef _Float16 half8 __attribute__((ext_vector_type(8)));
typedef _Float16 half2t __attribute__((ext_vector_type(2)));
typedef float f32x4 __attribute__((ext_vector_type(4)));

__device__ __forceinline__ float rcp_f(float v) { return __builtin_amdgcn_rcpf(v); }

// Layout assumptions (gfx950 mfma_f32_16x16x32_f16, guide-verified family):
//   A (16x32): lane holds row m = lane&15,  k = (lane>>4)*8 + e  (8 contig k)
//   B (32x16): lane holds col n = lane&15,  k = (lane>>4)*8 + e
//   D (16x16): lane holds col n = lane&15,  row m = (lane>>4)*4 + reg
// We compute D[batch][unit] = A(h)[batch][k] * B(W^T)[k][unit].
__global__ __launch_bounds__(512, 2) void gru_mfma_kernel(
    const float* __restrict__ x, const float* __restrict__ w_ih,
    const float* __restrict__ w_hh, const float* __restrict__ b_ih,
    const float* __restrict__ b_hh, const float* __restrict__ fc_w,
    const float* __restrict__ fc_b, float* __restrict__ out)
{
    const int tid  = threadIdx.x;
    const int w    = tid >> 6;     // wave 0..7
    const int lane = tid & 63;
    const int c    = lane & 15;    // unit-in-tile / batch-row for A
    const int g    = lane >> 4;    // k-group 0..3
    const int row0 = blockIdx.x * 2;

    __shared__ float    x_lds[2][1028];                          // m values, [b][t]: idx0 = 0.5
    __shared__ __align__(16) _Float16 h_lds[2][16][264];         // dbuf, 264 = 256+8 pad
    __shared__ float    dpart[2][8][2];

    // ---- stage m = (x+1)/2, with m[-1] := 0.5 at index 0 ----
    for (int i = tid; i < 2 * SL; i += 512) {
        int b = i >> 10, j = i & (SL - 1);
        x_lds[b][1 + j] = (x[(size_t)(row0 + b) * SL + j] + 1.0f) * 0.5f;
    }
    if (tid < 2) x_lds[tid][0] = 0.5f;
    for (int i = tid; i < 2 * 16 * 264; i += 512)
        ((_Float16*)h_lds)[i] = (_Float16)0.0f;

    // ---- persistent B fragments: W^T tiles as f16 (6 unit-tiles x 8 k-tiles) ----
    // frag f: unit-tile = (f>>1)*16 + 2*w + (f&1)   (f0,1=r  f2,3=z  f4,5=n)
    half8 B[6][8];
    #pragma unroll
    for (int f = 0; f < 6; ++f) {
        const int tile = (f >> 1) * 16 + 2 * w + (f & 1);
        const int u = tile * 16 + c;
        #pragma unroll
        for (int kt = 0; kt < 8; ++kt) {
            const float* p = w_hh + (size_t)u * NW + kt * 32 + g * 8;
            float4 lo = *(const float4*)p;
            float4 hi = *(const float4*)(p + 4);
            half8 hb;
            hb[0] = (_Float16)lo.x; hb[1] = (_Float16)lo.y;
            hb[2] = (_Float16)lo.z; hb[3] = (_Float16)lo.w;
            hb[4] = (_Float16)hi.x; hb[5] = (_Float16)hi.y;
            hb[6] = (_Float16)hi.z; hb[7] = (_Float16)hi.w;
            B[f][kt] = hb;
        }
    }

    // ---- per-lane gate constants for units u0 = 32w + c, u1 = u0 + 16 ----
    // c(m) = m*w_ih[u][0] + (1-m)*w_ih[u][1] + b_ih[u] (+ b_hh[u] for r,z)
    // packed (cm, cd) as f16 pairs to save VGPRs
    half2t pkr[2], pkz[2], pkn[2];
    float bhn[2], wd[2];
    #pragma unroll
    for (int p = 0; p < 2; ++p) {
        const int u = 32 * w + c + (p ? 16 : 0);
        float w0, w1, cm;
        w0 = w_ih[2 * u]; w1 = w_ih[2 * u + 1];
        cm = w1 + b_ih[u] + b_hh[u];
        pkr[p][0] = (_Float16)cm; pkr[p][1] = (_Float16)(w0 - w1);
        w0 = w_ih[2 * (NW + u)]; w1 = w_ih[2 * (NW + u) + 1];
        cm = w1 + b_ih[NW + u] + b_hh[NW + u];
        pkz[p][0] = (_Float16)cm; pkz[p][1] = (_Float16)(w0 - w1);
        w0 = w_ih[2 * (2 * NW + u)]; w1 = w_ih[2 * (2 * NW + u) + 1];
        cm = w1 + b_ih[2 * NW + u];
        pkn[p][0] = (_Float16)cm; pkn[p][1] = (_Float16)(w0 - w1);
        bhn[p] = b_hh[2 * NW + u];
        wd[p]  = fc_w[u] - fc_w[NW + u];
    }
    const float bd = fc_b[0] - fc_b[1];

    float h[2][2] = {{0.f, 0.f}, {0.f, 0.f}};
    float lp = 0.f;

    __syncthreads();

    #pragma unroll 1
    for (int t = 0; t < SL; ++t) {
        const int cur = t & 1, nxt = cur ^ 1;
        const float m0 = x_lds[0][t];
        const float m1 = x_lds[1][t];

        f32x4 acc[6];
        #pragma unroll
        for (int f = 0; f < 6; ++f) { f32x4 z = {0.f, 0.f, 0.f, 0.f}; acc[f] = z; }

        #pragma unroll
        for (int kt = 0; kt < 8; ++kt) {
            half8 A = *(const half8*)&h_lds[cur][c][kt * 32 + g * 8];
            #pragma unroll
            for (int f = 0; f < 6; ++f)
                acc[f] = __builtin_amdgcn_mfma_f32_16x16x32_f16(A, B[f][kt], acc[f], 0, 0, 0);
        }

        float hn[2][2];
        #pragma unroll
        for (int p = 0; p < 2; ++p) {
            const float cmr = (float)pkr[p][0], cdr = (float)pkr[p][1];
            const float cmz = (float)pkz[p][0], cdz = (float)pkz[p][1];
            const float cmn = (float)pkn[p][0], cdn = (float)pkn[p][1];
            #pragma unroll
            for (int r = 0; r < 2; ++r) {
                const float m  = r ? m1 : m0;
                const float vr = acc[p][r] + fmaf(m, cdr, cmr);
                const float rr = rcp_f(1.f + __expf(-vr));
                const float vz = acc[2 + p][r] + fmaf(m, cdz, cmz);
                const float zz = rcp_f(1.f + __expf(-vz));
                const float un = fmaf(rr, acc[4 + p][r] + bhn[p], fmaf(m, cdn, cmn));
                const float ng = fmaf(-2.f, rcp_f(1.f + __expf(2.f * un)), 1.f);
                const float v  = fmaf(zz, h[p][r] - ng, ng);
                hn[p][r] = v; h[p][r] = v;
            }
        }

        // output-head partial: d[b] = sum_u h[b][u] * wd[u]  (valid on lanes 0..15)
        float v0 = fmaf(hn[0][0], wd[0], hn[1][0] * wd[1]);
        float v1 = fmaf(hn[0][1], wd[0], hn[1][1] * wd[1]);
        v0 += __shfl_xor(v0, 1); v0 += __shfl_xor(v0, 2);
        v0 += __shfl_xor(v0, 4); v0 += __shfl_xor(v0, 8);
        v1 += __shfl_xor(v1, 1); v1 += __shfl_xor(v1, 2);
        v1 += __shfl_xor(v1, 4); v1 += __shfl_xor(v1, 8);
        if (lane == 0) { dpart[cur][w][0] = v0; dpart[cur][w][1] = v1; }

        if (g == 0) {
            h_lds[nxt][0][32 * w + c]      = (_Float16)hn[0][0];
            h_lds[nxt][0][32 * w + 16 + c] = (_Float16)hn[1][0];
            h_lds[nxt][1][32 * w + c]      = (_Float16)hn[0][1];
            h_lds[nxt][1][32 * w + 16 + c] = (_Float16)hn[1][1];
        }
        __syncthreads();

        if (w == 0 && lane < 2) {
            float d = bd;
            #pragma unroll
            for (int q = 0; q < 8; ++q) d += dpart[cur][q][lane];
            const float mt = x_lds[lane][t + 1];
            const float uu = (mt > 0.5f) ? -d : d;    // u = -x_t * d
            lp -= fmaxf(uu, 0.f) + logf(1.f + __expf(-fabsf(uu)));
        }
    }

    if (w == 0 && lane < 2) out[row0 + lane] = lp;
}

extern "C" void kernel_launch(void* const* d_in, const int* in_sizes, int n_in,
                              void* d_out, int out_size, void* d_ws, size_t ws_size,
                              hipStream_t stream) {
    const float* x    = (const float*)d_in[0];
    const float* w_ih = (const float*)d_in[1];
    const float* w_hh = (const float*)d_in[2];
    const float* b_ih = (const float*)d_in[3];
    const float* b_hh = (const float*)d_in[4];
    const float* fc_w = (const float*)d_in[5];
    const float* fc_b = (const float*)d_in[6];
    gru_mfma_kernel<<<256, 512, 0, stream>>>(
        x, w_ih, w_hh, b_ih, b_hh, fc_w, fc_b, (float*)d_out);
}